// Round 1
// baseline (863.541 us; speedup 1.0000x reference)
//
#include <hip/hip_runtime.h>
#include <cstdint>
#include <cstddef>

typedef int v4i __attribute__((ext_vector_type(4)));

#define HWSZ 3136
#define WID 56
#define CCH 256
#define BAT 32
#define NPIX (BAT*HWSZ)   /* 100352 */
#define KTOT 2304

// ---------------- pack weights + fused epilogue params ----------------
// w layout [O][C][3][3]; wpack[o][tap*256 + c] = sign(w)
// params: [0..255]=c1 (mult acc1), [256..511]=c2 (mult acc2), [512..767]=c3 (bias)
__global__ void pack_weights(const float* __restrict__ w,
                             const float* __restrict__ sc,
                             const float* __restrict__ g,
                             const float* __restrict__ bb,
                             const float* __restrict__ m,
                             const float* __restrict__ v,
                             int8_t* __restrict__ wpack,
                             float* __restrict__ params) {
    int o = blockIdx.x;
    int t = threadIdx.x;
    const float* wo = w + (size_t)o * KTOT;
    __shared__ float red[256];
    float s = 0.f;
    for (int i = t; i < KTOT; i += 256) {
        float val = wo[i];            // i = c*9 + tap
        s += fabsf(val);
        int c = i / 9, tap = i - c * 9;
        int8_t sgn = (val > 0.f) ? 1 : ((val < 0.f) ? -1 : 0);
        wpack[(size_t)o * KTOT + tap * 256 + c] = sgn;
    }
    red[t] = s;
    __syncthreads();
    for (int off = 128; off > 0; off >>= 1) {
        if (t < off) red[t] += red[t + off];
        __syncthreads();
    }
    if (t == 0) {
        float alpha = red[0] / (float)KTOT;
        float inv = rsqrtf(v[o] + 1e-5f);
        float cs = alpha * inv * g[o];
        params[o]         = cs;
        params[256 + o]   = cs * sc[o];
        params[512 + o]   = bb[o] - m[o] * inv * g[o];
    }
}

// ---------------- binarize x (NCHW fp32) -> a1,a2 (NHWC int8) ----------------
__global__ void binarize_nchw_to_nhwc(const float* __restrict__ x,
                                      const float* __restrict__ sh1,
                                      const float* __restrict__ sh2,
                                      int8_t* __restrict__ a1,
                                      int8_t* __restrict__ a2) {
    __shared__ int8_t s1[32][260];
    __shared__ int8_t s2[32][260];
    int b = blockIdx.y;
    int hw0 = blockIdx.x * 32;
    int t = threadIdx.x;
    int hw4 = (t & 7) * 4;
    int crow = t >> 3;   // 0..31
    for (int i = 0; i < 8; ++i) {
        int c = crow + 32 * i;
        float4 val = *(const float4*)(x + ((size_t)(b * CCH + c)) * HWSZ + hw0 + hw4);
        float f1 = sh1[c], f2 = sh2[c];
        float vv[4] = {val.x, val.y, val.z, val.w};
        for (int j = 0; j < 4; ++j) {
            float u1 = vv[j] + f1;
            float u2 = vv[j] + f2;
            s1[hw4 + j][c] = (u1 > 0.f) ? 1 : ((u1 < 0.f) ? -1 : 0);
            s2[hw4 + j][c] = (u2 > 0.f) ? 1 : ((u2 < 0.f) ? -1 : 0);
        }
    }
    __syncthreads();
    int c4 = (t & 63) * 4;
    for (int j = 0; j < 8; ++j) {
        int hw = (t >> 6) + 4 * j;
        uchar4 p1 = *(const uchar4*)&s1[hw][c4];
        uchar4 p2 = *(const uchar4*)&s2[hw][c4];
        size_t dst = ((size_t)(b * HWSZ + hw0 + hw)) * CCH + c4;
        *(uchar4*)(a1 + dst) = p1;
        *(uchar4*)(a2 + dst) = p2;
    }
}

// ---------------- binarize mid (NHWC fp32) -> a1,a2 (NHWC int8) ----------------
__global__ void binarize_flat(const float* __restrict__ xin,
                              const float* __restrict__ sh1,
                              const float* __restrict__ sh2,
                              int8_t* __restrict__ a1,
                              int8_t* __restrict__ a2) {
    size_t gidx = (size_t)blockIdx.x * blockDim.x + threadIdx.x;
    size_t idx = gidx * 4;
    int c = (int)(idx & 255);
    float4 v = *(const float4*)(xin + idx);
    float4 f1 = *(const float4*)(sh1 + c);
    float4 f2 = *(const float4*)(sh2 + c);
    uchar4 o1, o2;
    float a;
    a = v.x + f1.x; o1.x = (uint8_t)((a > 0.f) ? 1 : ((a < 0.f) ? -1 : 0));
    a = v.y + f1.y; o1.y = (uint8_t)((a > 0.f) ? 1 : ((a < 0.f) ? -1 : 0));
    a = v.z + f1.z; o1.z = (uint8_t)((a > 0.f) ? 1 : ((a < 0.f) ? -1 : 0));
    a = v.w + f1.w; o1.w = (uint8_t)((a > 0.f) ? 1 : ((a < 0.f) ? -1 : 0));
    a = v.x + f2.x; o2.x = (uint8_t)((a > 0.f) ? 1 : ((a < 0.f) ? -1 : 0));
    a = v.y + f2.y; o2.y = (uint8_t)((a > 0.f) ? 1 : ((a < 0.f) ? -1 : 0));
    a = v.z + f2.z; o2.z = (uint8_t)((a > 0.f) ? 1 : ((a < 0.f) ? -1 : 0));
    a = v.w + f2.w; o2.w = (uint8_t)((a > 0.f) ? 1 : ((a < 0.f) ? -1 : 0));
    *(uchar4*)(a1 + idx) = o1;
    *(uchar4*)(a2 + idx) = o2;
}

// ---------------- binarized implicit-GEMM conv, dual activation streams -------
// M = NPIX (pixels, NHWC), N = 256 (out ch), K = 2304 (tap*256 + c)
// SB==1: residual = x (NCHW), output -> mid (NHWC)
// SB==2: residual = mid (NHWC), output -> d_out (NCHW)
template<int SB>
__global__ __launch_bounds__(256)
void bingemm(const int8_t* __restrict__ a1g,
             const int8_t* __restrict__ a2g,
             const int8_t* __restrict__ wp,
             const float* __restrict__ params,
             const float* __restrict__ res,
             float* __restrict__ outp)
{
    __shared__ __align__(16) int8_t sA1[128 * 80];
    __shared__ __align__(16) int8_t sA2[128 * 80];
    __shared__ __align__(16) int8_t sB [64 * 80];
    int t = threadIdx.x;
    int o0 = blockIdx.x * 64;
    int m0 = blockIdx.y * 128;

    int rowA = t >> 2;           // 0..63 (also B staging row)
    int chunk = t & 3;
    int pb[2], ph[2], pw[2];
    for (int p = 0; p < 2; ++p) {
        int pix = m0 + rowA + p * 64;
        int b = pix / HWSZ;
        int hw = pix - b * HWSZ;
        int h = hw / WID;
        int w = hw - h * WID;
        pb[p] = b; ph[p] = h; pw[p] = w;
    }

    v4i acc1[2][4], acc2[2][4];
    for (int i = 0; i < 2; ++i)
        for (int j = 0; j < 4; ++j) {
            acc1[i][j] = (v4i){0, 0, 0, 0};
            acc2[i][j] = (v4i){0, 0, 0, 0};
        }

    int lane = t & 63;
    int wv = t >> 6;
    int ml = lane & 15;
    int kc = lane >> 4;

    for (int kt = 0; kt < 36; ++kt) {
        int tap = kt >> 2;
        int dh = tap / 3 - 1, dw = tap - (tap / 3) * 3 - 1;
        // --- A staging (both streams), 128 rows x 64B ---
        for (int p = 0; p < 2; ++p) {
            int h2 = ph[p] + dh, w2 = pw[p] + dw;
            v4i va = (v4i){0, 0, 0, 0};
            v4i vb = (v4i){0, 0, 0, 0};
            if ((unsigned)h2 < 56u && (unsigned)w2 < 56u) {
                size_t src = ((size_t)(pb[p] * HWSZ + h2 * WID + w2)) * 256
                             + ((kt & 3) * 64) + chunk * 16;
                va = *(const v4i*)(a1g + src);
                vb = *(const v4i*)(a2g + src);
            }
            int row = rowA + p * 64;
            *(v4i*)&sA1[row * 80 + chunk * 16] = va;
            *(v4i*)&sA2[row * 80 + chunk * 16] = vb;
        }
        // --- B staging: 64 rows(n) x 64B(k), pre-transposed wpack[o][k] ---
        {
            size_t src = (size_t)(o0 + rowA) * KTOT + kt * 64 + chunk * 16;
            *(v4i*)&sB[rowA * 80 + chunk * 16] = *(const v4i*)(wp + src);
        }
        __syncthreads();
        // --- fragments + MFMA ---
        v4i af1[2], af2[2], bf[4];
        for (int ms = 0; ms < 2; ++ms) {
            int row = wv * 32 + ms * 16 + ml;
            af1[ms] = *(const v4i*)&sA1[row * 80 + kc * 16];
            af2[ms] = *(const v4i*)&sA2[row * 80 + kc * 16];
        }
        for (int ns = 0; ns < 4; ++ns)
            bf[ns] = *(const v4i*)&sB[(ns * 16 + ml) * 80 + kc * 16];
        for (int ms = 0; ms < 2; ++ms)
            for (int ns = 0; ns < 4; ++ns) {
                acc1[ms][ns] = __builtin_amdgcn_mfma_i32_16x16x64_i8(af1[ms], bf[ns], acc1[ms][ns], 0, 0, 0);
                acc2[ms][ns] = __builtin_amdgcn_mfma_i32_16x16x64_i8(af2[ms], bf[ns], acc2[ms][ns], 0, 0, 0);
            }
        __syncthreads();
    }

    // --- epilogue: D layout col(n)=lane&15, row(m)=(lane>>4)*4+r ---
    for (int ns = 0; ns < 4; ++ns) {
        int o = o0 + ns * 16 + ml;
        float c1 = params[o], c2 = params[256 + o], c3 = params[512 + o];
        for (int ms = 0; ms < 2; ++ms) {
            int mbase = m0 + wv * 32 + ms * 16 + kc * 4;
            for (int r = 0; r < 4; ++r) {
                int pix = mbase + r;
                int b = pix / HWSZ;
                int hw = pix - b * HWSZ;
                float rv;
                if (SB == 1) rv = res[((size_t)(b * 256 + o)) * HWSZ + hw];
                else         rv = res[(size_t)pix * 256 + o];
                float val = (float)acc1[ms][ns][r] * c1
                          + (float)acc2[ms][ns][r] * c2 + c3 + rv;
                val = fminf(1.f, fmaxf(-1.f, val));
                if (SB == 1) outp[(size_t)pix * 256 + o] = val;
                else         outp[((size_t)(b * 256 + o)) * HWSZ + hw] = val;
            }
        }
    }
}

extern "C" void kernel_launch(void* const* d_in, const int* in_sizes, int n_in,
                              void* d_out, int out_size, void* d_ws, size_t ws_size,
                              hipStream_t stream) {
    const float* x    = (const float*)d_in[0];
    const float* sh11 = (const float*)d_in[1];
    const float* sh12 = (const float*)d_in[2];
    const float* w1   = (const float*)d_in[3];
    const float* sc1  = (const float*)d_in[4];
    const float* g1   = (const float*)d_in[5];
    const float* b1   = (const float*)d_in[6];
    const float* m1   = (const float*)d_in[7];
    const float* v1   = (const float*)d_in[8];
    const float* sh21 = (const float*)d_in[9];
    const float* sh22 = (const float*)d_in[10];
    const float* w2   = (const float*)d_in[11];
    const float* sc2  = (const float*)d_in[12];
    const float* g2   = (const float*)d_in[13];
    const float* b2   = (const float*)d_in[14];
    const float* m2   = (const float*)d_in[15];
    const float* v2   = (const float*)d_in[16];

    uint8_t* ws = (uint8_t*)d_ws;
    size_t off = 0;
    auto alloc = [&](size_t bytes) -> uint8_t* {
        uint8_t* p = ws + off;
        off += (bytes + 255) & ~(size_t)255;
        return p;
    };
    int8_t* a1  = (int8_t*)alloc((size_t)NPIX * 256);
    int8_t* a2  = (int8_t*)alloc((size_t)NPIX * 256);
    float*  mid = (float*)alloc((size_t)NPIX * 256 * 4);
    int8_t* wp1 = (int8_t*)alloc((size_t)256 * KTOT);
    int8_t* wp2 = (int8_t*)alloc((size_t)256 * KTOT);
    float*  par1 = (float*)alloc(3 * 256 * 4);
    float*  par2 = (float*)alloc(3 * 256 * 4);
    (void)ws_size; (void)in_sizes; (void)n_in; (void)out_size;

    pack_weights<<<256, 256, 0, stream>>>(w1, sc1, g1, b1, m1, v1, wp1, par1);
    pack_weights<<<256, 256, 0, stream>>>(w2, sc2, g2, b2, m2, v2, wp2, par2);
    binarize_nchw_to_nhwc<<<dim3(98, 32), 256, 0, stream>>>(x, sh11, sh12, a1, a2);
    bingemm<1><<<dim3(4, 784), 256, 0, stream>>>(a1, a2, wp1, par1, x, mid);
    binarize_flat<<<25088, 256, 0, stream>>>(mid, sh21, sh22, a1, a2);
    bingemm<2><<<dim3(4, 784), 256, 0, stream>>>(a1, a2, wp2, par2, mid, (float*)d_out);
}